// Round 7
// baseline (288.622 us; speedup 1.0000x reference)
//
#include <hip/hip_runtime.h>

#define NN 50000
#define NE 640000
#define NR 3
#define DH 128
#define ET (NR * NE)           // 1,920,000 edges total

#define BK 256                 // nodes per bucket
#define NBK 196                // buckets per relation: ceil(50000/256)
#define NBT (NR * NBK)         // 588 total buckets
#define NCH 512                // edge chunks
#define CH (ET / NCH)          // 3750 edges per chunk (exact)

typedef __attribute__((ext_vector_type(8))) short short8;
typedef __attribute__((ext_vector_type(4))) float f32x4;

__device__ __forceinline__ float bf2f(uint u) { return __uint_as_float(u << 16); }
__device__ __forceinline__ uint f2bf(float f) {
    uint u = __float_as_uint(f);
    u += 0x7fff + ((u >> 16) & 1);  // round-to-nearest-even
    return u >> 16;
}
__device__ __forceinline__ uint pack2(float a, float b) { return f2bf(a) | (f2bf(b) << 16); }

// ---------------- pass 1: per-chunk LDS histogram of 588 buckets ----------------
__global__ __launch_bounds__(256) void hist_kernel(const int* __restrict__ ei,
                                                   int* __restrict__ gcnt) {
    __shared__ int hist[NBT];
    int g = blockIdx.x, t = threadIdx.x;
    for (int i = t; i < NBT; i += 256) hist[i] = 0;
    __syncthreads();
    int e0 = g * CH;
    for (int i = t; i < CH; i += 256) {
        int e = e0 + i;
        int r = (e >= 2 * NE) ? 2 : (e >= NE ? 1 : 0);
        int le = e - r * NE;
        int dst = ei[r * 2 * NE + NE + le];
        atomicAdd(&hist[r * NBK + (dst >> 8)], 1);
    }
    __syncthreads();
    for (int i = t; i < NBT; i += 256) gcnt[g * NBT + i] = hist[i];
}

// ---------------- pass 2a: per-bucket scan over chunk counts ----------------
__global__ __launch_bounds__(256) void cscan_kernel(const int* __restrict__ gcnt,
                                                    int* __restrict__ gbase,
                                                    int* __restrict__ btot) {
    int b = blockIdx.x, t = threadIdx.x;  // 512 values, 2 per thread
    int v0 = gcnt[(2 * t) * NBT + b];
    int v1 = gcnt[(2 * t + 1) * NBT + b];
    int s = v0 + v1;
    int lane = t & 63, w = t >> 6;
    int sc = s;
#pragma unroll
    for (int d = 1; d < 64; d <<= 1) {
        int u = __shfl_up(sc, d);
        if (lane >= d) sc += u;
    }
    __shared__ int ws[4];
    if (lane == 63) ws[w] = sc;
    __syncthreads();
    int add = 0;
#pragma unroll
    for (int q = 0; q < 3; ++q)
        if (q < w) add += ws[q];
    int incl = sc + add;
    int excl = incl - s;
    gbase[(2 * t) * NBT + b] = excl;
    gbase[(2 * t + 1) * NBT + b] = excl + v0;
    if (t == 255) btot[b] = incl;
}

// ---------------- pass 2b: bucket-base exclusive scan (588 values) ----------------
__global__ __launch_bounds__(1024) void bscan_kernel(const int* __restrict__ btot,
                                                     int* __restrict__ bbase) {
    int t = threadIdx.x;
    int v = (t < NBT) ? btot[t] : 0;
    int lane = t & 63, w = t >> 6;
    int s = v;
#pragma unroll
    for (int d = 1; d < 64; d <<= 1) {
        int u = __shfl_up(s, d);
        if (lane >= d) s += u;
    }
    __shared__ int ws[16];
    if (lane == 63) ws[w] = s;
    __syncthreads();
    if (t < 16) {
        int wv = ws[t];
#pragma unroll
        for (int d = 1; d < 16; d <<= 1) {
            int u = __shfl_up(wv, d);
            if (t >= d) wv += u;
        }
        ws[t] = wv;
    }
    __syncthreads();
    int incl = s + (w == 0 ? 0 : ws[w - 1]);
    if (t < NBT) bbase[t] = incl - v;  // exclusive
}

// ---------------- pass 3: scatter pairs via LDS cursors (no global atomics) ----------------
__global__ __launch_bounds__(256) void scatter_kernel(const int* __restrict__ ei,
                                                      const int* __restrict__ gbase,
                                                      const int* __restrict__ bbase,
                                                      uint* __restrict__ pairs) {
    __shared__ int cur[NBT];
    int g = blockIdx.x, t = threadIdx.x;
    for (int i = t; i < NBT; i += 256) cur[i] = bbase[i] + gbase[g * NBT + i];
    __syncthreads();
    int e0 = g * CH;
    for (int i = t; i < CH; i += 256) {
        int e = e0 + i;
        int r = (e >= 2 * NE) ? 2 : (e >= NE ? 1 : 0);
        int le = e - r * NE;
        int src = ei[r * 2 * NE + le];
        int dst = ei[r * 2 * NE + NE + le];
        int b = r * NBK + (dst >> 8);
        int pos = atomicAdd(&cur[b], 1);
        pairs[pos] = ((uint)src << 8) | (uint)(dst & 255);
    }
}

// ---------------- level 2: per-bucket LDS histogram + scan + scatter ----------------
__global__ __launch_bounds__(256) void csr_kernel(const uint* __restrict__ pairs,
                                                  const int* __restrict__ btot,
                                                  const int* __restrict__ bbase,
                                                  int* __restrict__ csr,
                                                  int* __restrict__ offs,
                                                  int* __restrict__ deg) {
    int b = blockIdx.x;            // 0..587
    int r = b / NBK;
    int n0 = (b - r * NBK) * BK;   // first node (within relation)
    int cnt = btot[b];
    int base = bbase[b];
    int t = threadIdx.x;

    __shared__ int hist[BK];
    __shared__ int cur[BK];
    __shared__ int ws[4];
    hist[t] = 0;
    __syncthreads();
    const uint* pp = pairs + base;
    for (int i = t; i < cnt; i += 256) atomicAdd(&hist[pp[i] & 255u], 1);
    __syncthreads();

    int lane = t & 63, w = t >> 6;
    int v = hist[t], s = v;
#pragma unroll
    for (int d = 1; d < 64; d <<= 1) {
        int u = __shfl_up(s, d);
        if (lane >= d) s += u;
    }
    if (lane == 63) ws[w] = s;
    __syncthreads();
    int add = 0;
#pragma unroll
    for (int q = 0; q < 3; ++q)
        if (q < w) add += ws[q];
    int excl = s + add - v;

    int node = n0 + t;
    if (node < NN) {
        offs[r * NN + node] = base + excl;  // absolute into csr
        deg[r * NN + node] = v;
    }
    cur[t] = excl;
    __syncthreads();

    for (int i = t; i < cnt; i += 256) {
        uint pk = pp[i];
        int pos = atomicAdd(&cur[pk & 255u], 1);
        csr[base + pos] = (int)(pk >> 8);
    }
}

// ---------------- fused preprocessing: conv (x->bf16) + weight pack + bias sum
__global__ __launch_bounds__(256) void prep_all(const float* __restrict__ x,
                                                const float* __restrict__ Wn,
                                                const float* __restrict__ Wr,
                                                const float* __restrict__ bc,
                                                const float* __restrict__ linW,
                                                ushort* __restrict__ xb,
                                                ushort* __restrict__ Wpack,
                                                float* __restrict__ bsum) {
    int bid = blockIdx.x;
    if (bid < 6251) {  // conv: NN*DH/4 = 1,600,000 float4s
        int gid = bid * 256 + threadIdx.x;
        if (gid >= NN * DH / 4) return;
        float4 v = ((const float4*)x)[gid];
        uint2 o;
        o.x = pack2(v.x, v.y);
        o.y = pack2(v.z, v.w);
        ((uint2*)xb)[gid] = o;
    } else if (bid < 6317) {  // weight pack: 264 frags x 64 lanes
        int tid = (bid - 6251) * 256 + threadIdx.x;
        if (tid >= 264 * 64) return;
        int f = tid >> 6, lane = tid & 63;
        int l15 = lane & 15, l4 = lane >> 4;
        ushort hi8[8], lo8[8];
        if (f < 256) {
            int layer = f >> 7, seg = (f >> 5) & 3, kc = (f >> 3) & 3, nb = f & 7;
            int col = nb * 16 + l15;
            int kb = kc * 32 + l4 * 8;
#pragma unroll
            for (int e = 0; e < 8; ++e) {
                int k = kb + e;
                float v;
                if (seg < 3) {
                    v = Wn[(((size_t)layer * 3 + seg) * 128 + k) * 128 + col];
                } else {
                    const float* base = Wr + (size_t)layer * 3 * 16384;
                    v = base[k * 128 + col] + base[16384 + k * 128 + col] +
                        base[32768 + k * 128 + col];
                }
                uint h = f2bf(v);
                float rem = v - bf2f(h);
                hi8[e] = (ushort)h;
                lo8[e] = (ushort)f2bf(rem);
            }
        } else {
            int g = f - 256;
            int kc = g >> 1, nb = g & 1;
            int col = nb * 16 + l15;
            int kb = kc * 32 + l4 * 8;
#pragma unroll
            for (int e = 0; e < 8; ++e) {
                float v = linW[(kb + e) * 32 + col];
                uint h = f2bf(v);
                float rem = v - bf2f(h);
                hi8[e] = (ushort)h;
                lo8[e] = (ushort)f2bf(rem);
            }
        }
        *(short8*)(Wpack + (size_t)f * 1024 + lane * 8) = *(short8*)hi8;
        *(short8*)(Wpack + (size_t)f * 1024 + 512 + lane * 8) = *(short8*)lo8;
    } else {  // bias sum: 2 layers x 128
        int tid = threadIdx.x;
        int l = tid >> 7, j = tid & 127;
        const float* bb = bc + l * 3 * DH;
        bsum[tid] = bb[j] + bb[DH + j] + bb[2 * DH + j];
    }
}

// ---------------- fused layer: gather-aggregate into LDS + MFMA GEMM
// 512 threads = 8 waves; block tile = 64 nodes x 128 cols.
// Wave w: gathers means for nodes w*8..w*8+7 per relation; owns col-block w*16 in MFMA.
template <bool LAST>
__global__ __launch_bounds__(512, 4) void layer_fused(
    const ushort* __restrict__ tb,   // [NN][128] bf16 node table (input h)
    void* __restrict__ h_out,        // LAST ? float*[NN][32] : ushort*[NN][128]
    const int* __restrict__ csr,
    const int* __restrict__ offs,
    const int* __restrict__ deg,
    const ushort* __restrict__ Wp,   // this layer: [4 seg][4 kc][8 nb][2][64][8]
    const float* __restrict__ bsum,  // [128] fp32, this layer
    const ushort* __restrict__ lWp,  // [4 kc][2 nb][2][64][8] (LAST)
    const float* __restrict__ linb)  // [32] (LAST)
{
    __shared__ ushort As[64][136];

    const int t = threadIdx.x, lane = t & 63, w = t >> 6;
    const int l15 = lane & 15, l4 = lane >> 4;
    const int eg = lane >> 4, cs = lane & 15;
    const int row0 = blockIdx.x * 64;

    f32x4 acc[4];
    {
        float4 bv = *(const float4*)(bsum + w * 16 + l4 * 4);
#pragma unroll
        for (int rt = 0; rt < 4; ++rt) acc[rt] = f32x4{bv.x, bv.y, bv.z, bv.w};
    }

    for (int seg = 0; seg < 4; ++seg) {
        __syncthreads();  // As free (previous seg's MFMA reads done)
        if (seg < NR) {
            // prefetch offs/deg for this wave's 8 nodes (lane nl holds node w*8+nl)
            int nl = lane & 7;
            int nodev = row0 + w * 8 + nl;
            int clamped = min(nodev, NN - 1);
            int widv = seg * NN + clamped;
            int vo = offs[widv];
            int vd = (nodev < NN) ? deg[widv] : 0;
#pragma unroll
            for (int i = 0; i < 8; ++i) {
                int base = __builtin_amdgcn_readlane(vo, i);
                int d = __builtin_amdgcn_readlane(vd, i);
                const int* lst = csr + base;
                float a[8] = {0.f, 0.f, 0.f, 0.f, 0.f, 0.f, 0.f, 0.f};
                for (int e = 0; e < d; e += 16) {  // 16 edges/iter, 4 dwordx4 in flight
                    uint4 v[4];
                    int ee[4];
#pragma unroll
                    for (int q = 0; q < 4; ++q) {
                        ee[q] = e + q * 4 + eg;
                        int idx = lst[min(ee[q], d - 1)];
                        v[q] = *(const uint4*)(tb + (size_t)idx * DH + cs * 8);
                    }
#pragma unroll
                    for (int q = 0; q < 4; ++q) {
                        if (ee[q] < d) {
                            a[0] += bf2f(v[q].x & 0xffffu);
                            a[1] += bf2f(v[q].x >> 16);
                            a[2] += bf2f(v[q].y & 0xffffu);
                            a[3] += bf2f(v[q].y >> 16);
                            a[4] += bf2f(v[q].z & 0xffffu);
                            a[5] += bf2f(v[q].z >> 16);
                            a[6] += bf2f(v[q].w & 0xffffu);
                            a[7] += bf2f(v[q].w >> 16);
                        }
                    }
                }
#pragma unroll
                for (int j = 0; j < 8; ++j) {
                    a[j] += __shfl_xor(a[j], 16);
                    a[j] += __shfl_xor(a[j], 32);
                }
                if (eg == 0) {
                    float inv = 1.f / fmaxf((float)d, 1.f);
                    uint4 o;
                    o.x = pack2(a[0] * inv, a[1] * inv);
                    o.y = pack2(a[2] * inv, a[3] * inv);
                    o.z = pack2(a[4] * inv, a[5] * inv);
                    o.w = pack2(a[6] * inv, a[7] * inv);
                    *(uint4*)(&As[w * 8 + i][cs * 8]) = o;
                }
            }
        } else {
            // stage root rows from tb: 64 rows x 16 chunks of 16B, 512 threads x 2
#pragma unroll
            for (int it = 0; it < 2; ++it) {
                int q = it * 512 + t;
                int r = q >> 4, c = q & 15;
                int node = row0 + r;
                uint4 v = make_uint4(0, 0, 0, 0);
                if (node < NN) v = *(const uint4*)(tb + (size_t)node * DH + c * 8);
                *(uint4*)(&As[r][c * 8]) = v;
            }
        }
        __syncthreads();
        const ushort* wseg = Wp + (size_t)seg * 32768;
#pragma unroll
        for (int kc = 0; kc < 4; ++kc) {
            const ushort* wkc = wseg + kc * 8192 + w * 1024;
            short8 bh = *(const short8*)(wkc + lane * 8);
            short8 bl = *(const short8*)(wkc + 512 + lane * 8);
#pragma unroll
            for (int rt = 0; rt < 4; ++rt) {
                short8 a = *(const short8*)(&As[rt * 16 + l15][kc * 32 + l4 * 8]);
                acc[rt] = __builtin_amdgcn_mfma_f32_16x16x32_bf16(bh, a, acc[rt], 0, 0, 0);
                acc[rt] = __builtin_amdgcn_mfma_f32_16x16x32_bf16(bl, a, acc[rt], 0, 0, 0);
            }
        }
    }

    if constexpr (!LAST) {
        ushort* hb = (ushort*)h_out;
#pragma unroll
        for (int rt = 0; rt < 4; ++rt) {
            int node = row0 + rt * 16 + l15;
            if (node < NN) {
                uint2 o;
                o.x = pack2(fmaxf(acc[rt][0], 0.f), fmaxf(acc[rt][1], 0.f));
                o.y = pack2(fmaxf(acc[rt][2], 0.f), fmaxf(acc[rt][3], 0.f));
                *(uint2*)(hb + (size_t)node * DH + w * 16 + l4 * 4) = o;
            }
        }
    } else {
        __syncthreads();  // all MFMA reads of As done before overwrite with h2
#pragma unroll
        for (int rt = 0; rt < 4; ++rt) {
            uint2 o;
            o.x = pack2(fmaxf(acc[rt][0], 0.f), fmaxf(acc[rt][1], 0.f));
            o.y = pack2(fmaxf(acc[rt][2], 0.f), fmaxf(acc[rt][3], 0.f));
            *(uint2*)(&As[rt * 16 + l15][w * 16 + l4 * 4]) = o;
        }
        __syncthreads();
        // out[64x32] = relu(h2) @ linW + linb; wave w: rows rt=w>>1, col-block nb=w&1
        int rt = w >> 1, nb = w & 1;
        f32x4 acc2;
        {
            float4 c0 = *(const float4*)(linb + nb * 16 + l4 * 4);
            acc2 = f32x4{c0.x, c0.y, c0.z, c0.w};
        }
#pragma unroll
        for (int kc = 0; kc < 4; ++kc) {
            short8 a = *(const short8*)(&As[rt * 16 + l15][kc * 32 + l4 * 8]);
            const ushort* lw = lWp + (kc * 2 + nb) * 1024;
            short8 bh = *(const short8*)(lw + lane * 8);
            short8 bl = *(const short8*)(lw + 512 + lane * 8);
            acc2 = __builtin_amdgcn_mfma_f32_16x16x32_bf16(bh, a, acc2, 0, 0, 0);
            acc2 = __builtin_amdgcn_mfma_f32_16x16x32_bf16(bl, a, acc2, 0, 0, 0);
        }
        float* outp = (float*)h_out;
        int node = row0 + rt * 16 + l15;
        if (node < NN) {
            *(f32x4*)(outp + (size_t)node * 32 + nb * 16 + l4 * 4) = acc2;
        }
    }
}

extern "C" void kernel_launch(void* const* d_in, const int* in_sizes, int n_in,
                              void* d_out, int out_size, void* d_ws, size_t ws_size,
                              hipStream_t stream) {
    const float* x = (const float*)d_in[0];
    const int* ei = (const int*)d_in[1];
    const float* Wn = (const float*)d_in[2];
    const float* Wr = (const float*)d_in[3];
    const float* bc = (const float*)d_in[4];
    const float* linW = (const float*)d_in[5];
    const float* linb = (const float*)d_in[6];
    float* out = (float*)d_out;

    char* p = (char*)d_ws;
    int* gcnt = (int*)p;     p += (size_t)NCH * NBT * 4;      // 1.2 MB
    int* gbase = (int*)p;    p += (size_t)NCH * NBT * 4;      // 1.2 MB
    int* btot = (int*)p;     p += 4096;
    int* bbase = (int*)p;    p += 4096;
    int* offs = (int*)p;     p += (size_t)NR * NN * 4;
    int* deg = (int*)p;      p += (size_t)NR * NN * 4;
    int* csr = (int*)p;      p += (size_t)ET * 4;             // 7.7 MB
    uint* pairs = (uint*)p;  p += (size_t)ET * 4;             // 7.7 MB
    ushort* Wpack = (ushort*)p; p += (size_t)264 * 1024 * 2;  // 540 KB
    float* bsum = (float*)p; p += 4096;
    ushort* xb = (ushort*)p;  p += (size_t)NN * DH * 2;       // 12.8 MB
    ushort* h1b = (ushort*)p; p += (size_t)NN * DH * 2;       // 12.8 MB

    hist_kernel<<<NCH, 256, 0, stream>>>(ei, gcnt);
    cscan_kernel<<<NBT, 256, 0, stream>>>(gcnt, gbase, btot);
    bscan_kernel<<<1, 1024, 0, stream>>>(btot, bbase);
    scatter_kernel<<<NCH, 256, 0, stream>>>(ei, gbase, bbase, pairs);
    csr_kernel<<<NBT, 256, 0, stream>>>(pairs, btot, bbase, csr, offs, deg);
    prep_all<<<6318, 256, 0, stream>>>(x, Wn, Wr, bc, linW, xb, Wpack, bsum);

    int lb = (NN + 63) / 64;  // 782 blocks x 512 threads

    layer_fused<false><<<lb, 512, 0, stream>>>(xb, h1b, csr, offs, deg,
                                               Wpack, bsum, nullptr, nullptr);
    layer_fused<true><<<lb, 512, 0, stream>>>(h1b, out, csr, offs, deg,
                                              Wpack + (size_t)128 * 1024, bsum + DH,
                                              Wpack + (size_t)256 * 1024, linb);
}